// Round 1
// baseline (821.228 us; speedup 1.0000x reference)
//
#include <hip/hip_runtime.h>
#include <hip/hip_bf16.h>

// Problem constants
#define BSZ   512
#define ENCD  2048
#define DECD  1024
#define TST   12
#define PREDT 24
#define INDIM 2061
#define KPAD  2112      // INDIM padded to multiple of 64
#define G4    4096      // 4*DEC
#define KH    24576     // DEC*PRED

typedef __attribute__((ext_vector_type(8))) short s8v;
typedef __attribute__((ext_vector_type(4))) float f4v;

__device__ __forceinline__ short bf16_of(float f) {
  union { float f; unsigned u; } x; x.f = f;
  unsigned r = x.u + 0x7fffu + ((x.u >> 16) & 1u);  // RNE
  return (short)(r >> 16);
}

__device__ __forceinline__ float sigf(float x) {
  return 1.f / (1.f + __expf(-x));
}

// LDS swizzle: row stride 128 B (BK=64 bf16). XOR row-bits into 16B-slot index.
__device__ __forceinline__ int lds_off(int row, int colb) {
  return row * 128 + (colb ^ ((row & 7) << 4));
}

// ---------------- prep kernels ----------------

__global__ void prep_x(const float* __restrict__ enc, const float* __restrict__ oni,
                       const float* __restrict__ ssi, short* __restrict__ x_bf) {
  int idx = blockIdx.x * 256 + threadIdx.x;
  if (idx >= BSZ * KPAD) return;
  int b = idx / KPAD, k = idx % KPAD;
  float v = 0.f;
  if (k < ENCD) v = enc[b * ENCD + k];
  else if (k == ENCD) v = oni[b];
  else if (k < INDIM) v = ssi[b * TST + (k - ENCD - 1)];
  x_bf[idx] = bf16_of(v);
}

__global__ void prep_whh(const float* __restrict__ w, short* __restrict__ wb) {
  int base = (blockIdx.x * 256 + threadIdx.x) * 8;
  f4v f0 = *(const f4v*)(w + base);
  f4v f1 = *(const f4v*)(w + base + 4);
  s8v v;
#pragma unroll
  for (int j = 0; j < 4; ++j) { v[j] = bf16_of(f0[j]); v[4 + j] = bf16_of(f1[j]); }
  *(s8v*)(wb + base) = v;
}

// ---------------- generic GEMM: C(MxN) = A(bf16 MxK) @ Bw(fp32 NxK)^T ----------------
// EPI 0: Cf = acc + bias1 + bias2            (x_proj)
// EPI 1: Cf[z] = acc (split-K partials)      (head1)
// EPI 2: Cf = sigmoid(acc + bias1)           (head2 -> d_out)

template <int EPI, bool ALB>
__global__ __launch_bounds__(256, 2) void gemm_k(
    const short* __restrict__ A, int lda,
    const float* __restrict__ Bw, int ldb, int kreal, int kchunk, int ntiles,
    const float* __restrict__ bias1, const float* __restrict__ bias2,
    float* __restrict__ Cf, int ldc) {
  __shared__ __align__(16) short lA[128 * 64];
  __shared__ __align__(16) short lB[128 * 64];
  int tid = threadIdx.x;
  int lane = tid & 63, wid = tid >> 6;
  int wr = wid >> 1, wc = wid & 1;
  int bm = blockIdx.x * 128, bn = blockIdx.y * 128;
  int k0 = blockIdx.z * kchunk;
  size_t zoff = (size_t)blockIdx.z * BSZ * (size_t)ldc;

  f4v acc[4][4] = {};

  for (int kt = 0; kt < ntiles; ++kt) {
    int kk = k0 + kt * 64;
    // stage A (bf16 direct): 128x64, 4 chunks of 8 per thread
#pragma unroll
    for (int i = 0; i < 4; ++i) {
      int c = tid + i * 256;
      int r = c >> 3, kc = c & 7;
      s8v v = *(const s8v*)(A + (size_t)(bm + r) * lda + kk + kc * 8);
      *(s8v*)((char*)lA + lds_off(r, kc * 16)) = v;
    }
    // stage B (fp32 -> bf16)
#pragma unroll
    for (int i = 0; i < 4; ++i) {
      int c = tid + i * 256;
      int r = c >> 3, kc = c & 7;
      const float* src = Bw + (size_t)(bn + r) * ldb + kk + kc * 8;
      s8v v;
      if (ALB) {
        f4v f0 = *(const f4v*)src;
        f4v f1 = *(const f4v*)(src + 4);
#pragma unroll
        for (int j = 0; j < 4; ++j) { v[j] = bf16_of(f0[j]); v[4 + j] = bf16_of(f1[j]); }
      } else {
#pragma unroll
        for (int j = 0; j < 8; ++j) {
          int kg = kk + kc * 8 + j;
          float f = (kg < kreal) ? src[j] : 0.f;
          v[j] = bf16_of(f);
        }
      }
      *(s8v*)((char*)lB + lds_off(r, kc * 16)) = v;
    }
    __syncthreads();
#pragma unroll
    for (int ks = 0; ks < 2; ++ks) {
      int colb = ks * 64 + (lane >> 4) * 16;
      s8v af[4], bfr[4];
#pragma unroll
      for (int mi = 0; mi < 4; ++mi) {
        int r = wr * 64 + mi * 16 + (lane & 15);
        af[mi] = *(const s8v*)((char*)lA + lds_off(r, colb));
      }
#pragma unroll
      for (int ni = 0; ni < 4; ++ni) {
        int r = wc * 64 + ni * 16 + (lane & 15);
        bfr[ni] = *(const s8v*)((char*)lB + lds_off(r, colb));
      }
#pragma unroll
      for (int mi = 0; mi < 4; ++mi)
#pragma unroll
        for (int ni = 0; ni < 4; ++ni)
          acc[mi][ni] = __builtin_amdgcn_mfma_f32_16x16x32_bf16(af[mi], bfr[ni], acc[mi][ni], 0, 0, 0);
    }
    __syncthreads();
  }

#pragma unroll
  for (int mi = 0; mi < 4; ++mi)
#pragma unroll
    for (int ni = 0; ni < 4; ++ni)
#pragma unroll
      for (int j = 0; j < 4; ++j) {
        int row = bm + wr * 64 + mi * 16 + (lane >> 4) * 4 + j;
        int col = bn + wc * 64 + ni * 16 + (lane & 15);
        float v = acc[mi][ni][j];
        if (EPI == 0) {
          Cf[(size_t)row * ldc + col] = v + bias1[col] + bias2[col];
        } else if (EPI == 1) {
          Cf[zoff + (size_t)row * ldc + col] = v;
        } else {
          Cf[(size_t)row * ldc + col] = sigf(v + bias1[col]);
        }
      }
}

// ---------------- LSTM step ----------------
// Block: 64 batch rows x 32 d-cols (x4 gates = 128 GEMM cols). grid (8, 32).
__global__ __launch_bounds__(256, 2) void lstm_step_k(
    const short* __restrict__ h_in, const short* __restrict__ whh_bf,
    const float* __restrict__ x_proj, float* __restrict__ c_st,
    short* __restrict__ h_out, short* __restrict__ hs_bf, int tstep) {
  __shared__ __align__(16) char smem[32768];
  short* lA = (short*)smem;            // 64x64 bf16 (8 KB)
  short* lB = (short*)(smem + 8192);   // 128x64 bf16 (16 KB)
  float* gl = (float*)smem;            // 64x128 fp32 (32 KB), reused after compute

  int tid = threadIdx.x;
  int lane = tid & 63, wid = tid >> 6;
  int wr = wid >> 1, wc = wid & 1;
  int bm = blockIdx.x * 64;
  int d0 = blockIdx.y * 32;

  f4v acc[2][4] = {};

  for (int kt = 0; kt < 16; ++kt) {
    int kk = kt * 64;
#pragma unroll
    for (int i = 0; i < 2; ++i) {
      int c = tid + i * 256;
      int r = c >> 3, kc = c & 7;
      s8v v = *(const s8v*)(h_in + (size_t)(bm + r) * DECD + kk + kc * 8);
      *(s8v*)((char*)lA + lds_off(r, kc * 16)) = v;
    }
#pragma unroll
    for (int i = 0; i < 4; ++i) {
      int c = tid + i * 256;
      int r = c >> 3, kc = c & 7;
      int grow = (r >> 5) * DECD + d0 + (r & 31);
      s8v v = *(const s8v*)(whh_bf + (size_t)grow * DECD + kk + kc * 8);
      *(s8v*)((char*)lB + lds_off(r, kc * 16)) = v;
    }
    __syncthreads();
#pragma unroll
    for (int ks = 0; ks < 2; ++ks) {
      int colb = ks * 64 + (lane >> 4) * 16;
      s8v af[2], bfr[4];
#pragma unroll
      for (int mi = 0; mi < 2; ++mi) {
        int r = wr * 32 + mi * 16 + (lane & 15);
        af[mi] = *(const s8v*)((char*)lA + lds_off(r, colb));
      }
#pragma unroll
      for (int ni = 0; ni < 4; ++ni) {
        int r = wc * 64 + ni * 16 + (lane & 15);
        bfr[ni] = *(const s8v*)((char*)lB + lds_off(r, colb));
      }
#pragma unroll
      for (int mi = 0; mi < 2; ++mi)
#pragma unroll
        for (int ni = 0; ni < 4; ++ni)
          acc[mi][ni] = __builtin_amdgcn_mfma_f32_16x16x32_bf16(af[mi], bfr[ni], acc[mi][ni], 0, 0, 0);
    }
    __syncthreads();
  }

  // spill gates to LDS (fp32 64x128)
#pragma unroll
  for (int mi = 0; mi < 2; ++mi)
#pragma unroll
    for (int ni = 0; ni < 4; ++ni)
#pragma unroll
      for (int j = 0; j < 4; ++j) {
        int row = wr * 32 + mi * 16 + (lane >> 4) * 4 + j;
        int col = wc * 64 + ni * 16 + (lane & 15);
        gl[row * 128 + col] = acc[mi][ni][j];
      }
  __syncthreads();

  // elementwise LSTM cell: 64x32 = 2048 items
#pragma unroll
  for (int i = 0; i < 8; ++i) {
    int item = tid + i * 256;
    int m = item >> 5, j = item & 31;
    int b = bm + m, d = d0 + j;
    size_t xb = (size_t)b * G4 + d;
    float gi = gl[m * 128 + j]      + x_proj[xb];
    float gf = gl[m * 128 + 32 + j] + x_proj[xb + DECD];
    float gg = gl[m * 128 + 64 + j] + x_proj[xb + 2 * DECD];
    float go = gl[m * 128 + 96 + j] + x_proj[xb + 3 * DECD];
    size_t cd = (size_t)b * DECD + d;
    float cn = sigf(gf) * c_st[cd] + sigf(gi) * tanhf(gg);
    float h = sigf(go) * tanhf(cn);
    c_st[cd] = cn;
    short hb = bf16_of(h);
    h_out[cd] = hb;
    hs_bf[(size_t)b * KH + (size_t)d * PREDT + tstep] = hb;
  }
}

// ---------------- head1 reduce: z1 = sigmoid(sum parts + b_l1) ----------------
__global__ void reduce_head1(const float* __restrict__ part, const float* __restrict__ b_l1,
                             short* __restrict__ z1_bf) {
  int idx = blockIdx.x * 256 + threadIdx.x;  // over 512*1024
  int n = idx & (DECD - 1);
  float s = b_l1[n];
#pragma unroll
  for (int z = 0; z < 8; ++z) s += part[(size_t)z * (BSZ * DECD) + idx];
  z1_bf[idx] = bf16_of(sigf(s));
}

// ---------------- launch ----------------

extern "C" void kernel_launch(void* const* d_in, const int* in_sizes, int n_in,
                              void* d_out, int out_size, void* d_ws, size_t ws_size,
                              hipStream_t stream) {
  const float* enc  = (const float*)d_in[0];
  const float* oni  = (const float*)d_in[1];
  const float* ssi  = (const float*)d_in[2];
  const float* W_ih = (const float*)d_in[3];
  const float* b_ih = (const float*)d_in[4];
  const float* W_hh = (const float*)d_in[5];
  const float* b_hh = (const float*)d_in[6];
  const float* W_l1 = (const float*)d_in[7];
  const float* b_l1 = (const float*)d_in[8];
  const float* W_l2 = (const float*)d_in[9];
  const float* b_l2 = (const float*)d_in[10];
  float* out = (float*)d_out;

  char* ws = (char*)d_ws;
  size_t off = 0;
  auto carve = [&](size_t bytes) { char* p = ws + off; off += (bytes + 255) & ~(size_t)255; return p; };
  short* x_bf   = (short*)carve((size_t)BSZ * KPAD * 2);       // 2.16 MB
  float* x_proj = (float*)carve((size_t)BSZ * G4 * 4);         // 8.39 MB
  short* h0     = (short*)carve((size_t)BSZ * DECD * 2);       // 1.05 MB
  short* h1     = (short*)carve((size_t)BSZ * DECD * 2);       // 1.05 MB
  float* c_st   = (float*)carve((size_t)BSZ * DECD * 4);       // 2.10 MB
  short* whh_bf = (short*)carve((size_t)G4 * DECD * 2);        // 8.39 MB
  short* hs_bf  = (short*)carve((size_t)BSZ * KH * 2);         // 25.2 MB
  float* part   = (float*)carve((size_t)8 * BSZ * DECD * 4);   // 16.8 MB
  short* z1_bf  = (short*)carve((size_t)BSZ * DECD * 2);       // 1.05 MB
  (void)ws_size; (void)in_sizes; (void)n_in; (void)out_size;

  hipMemsetAsync(h0, 0, (size_t)BSZ * DECD * 2, stream);
  hipMemsetAsync(c_st, 0, (size_t)BSZ * DECD * 4, stream);

  prep_x<<<(BSZ * KPAD) / 256, 256, 0, stream>>>(enc, oni, ssi, x_bf);
  prep_whh<<<(G4 * DECD) / (256 * 8), 256, 0, stream>>>(W_hh, whh_bf);

  // x_proj = x @ W_ih^T + b_ih + b_hh
  gemm_k<0, false><<<dim3(4, 32, 1), 256, 0, stream>>>(
      x_bf, KPAD, W_ih, INDIM, INDIM, KPAD, KPAD / 64, b_ih, b_hh, x_proj, G4);

  // 24 LSTM steps (h double-buffered)
  short* hbuf[2] = {h0, h1};
  for (int t = 0; t < PREDT; ++t) {
    lstm_step_k<<<dim3(8, 32), 256, 0, stream>>>(
        hbuf[t & 1], whh_bf, x_proj, c_st, hbuf[(t + 1) & 1], hs_bf, t);
  }

  // head1: split-K=8 partials then reduce(+bias+sigmoid) -> z1 bf16
  gemm_k<1, true><<<dim3(4, 8, 8), 256, 0, stream>>>(
      hs_bf, KH, W_l1, KH, KH, KH / 8, KH / 8 / 64, nullptr, nullptr, part, DECD);
  reduce_head1<<<(BSZ * DECD) / 256, 256, 0, stream>>>(part, b_l1, z1_bf);

  // head2: out = sigmoid(z1 @ W_l2^T + b_l2)
  gemm_k<2, true><<<dim3(4, 8, 1), 256, 0, stream>>>(
      z1_bf, DECD, W_l2, DECD, DECD, DECD, DECD / 64, b_l2, nullptr, out, DECD);
}